// Round 20
// baseline (235.710 us; speedup 1.0000x reference)
//
#include <hip/hip_runtime.h>
#include <stdint.h>

#define NN    50000
#define NE    800000
#define FD    128
#define NLAY  4
#define NLIN  256
#define NOUTF 10
#define NGR   64
#define NBKT  196     // ceil(NN/256) buckets of 256 nodes
#define MAXB  8192    // per-bucket capacity incl. 16-padding (mean ~6100 -> safe)
#define GEMMB 782     // ceil(NN/64) gemm blocks
#define POOLB 512     // NGR * 8 pool blocks
#define PLSZ  ((size_t)(NN+1)*64)   // bytes per t-plane (64 B half-rows + sentinel)
#define AGGB  6256    // ceil((NN/16)/4)*8 — covers all (node-block, plane) pairs

typedef _Float16 half8  __attribute__((ext_vector_type(8)));
typedef _Float16 half4  __attribute__((ext_vector_type(4)));
typedef _Float16 half2t __attribute__((ext_vector_type(2)));
typedef float    f32x4  __attribute__((ext_vector_type(4)));

__device__ __forceinline__ int ld_idx(const void* p, int flag, long i){
    return flag ? (int)((const long long*)p)[i] : ((const int*)p)[i];
}

// ---------------- merged prologue: prep_w | zero(bktCur+gbuf) | sentinel | detect ----------
// If int64 (values < 2^31), every odd 32-bit word of edge_index is 0.
__global__ __launch_bounds__(256) void pre_k(const unsigned* __restrict__ eidx_u,
                                             const float* __restrict__ Ws,
                                             _Float16* __restrict__ WT,
                                             int* __restrict__ zbase, int zn, int zb,
                                             unsigned char* __restrict__ t,
                                             float* __restrict__ scl,
                                             int* __restrict__ flag){
    __shared__ int any;
    const int b = blockIdx.x, tid = threadIdx.x;
    if (b < 256){
        // WT[l][c][k] = Ws[l][k][c]
        int idx = b*256 + tid;
        int l = idx >> 14;
        int r = idx & 16383;
        int c = r >> 7, k = r & 127;
        WT[idx] = (_Float16)Ws[(l<<14) + (k<<7) + c];
    } else if (b < 256 + zb){
        int i = (b-256)*256 + tid;
        if (i < zn) zbase[i] = 0;
    } else if (b == 256 + zb){
        // zero-sentinel half-rows (row NN) of both planes + sentinel scale
        if (tid < 16) ((int*)(t + (size_t)NN*64))[tid] = 0;
        else if (tid < 32) ((int*)(t + PLSZ + (size_t)NN*64))[tid-16] = 0;
        if (tid == 0) scl[NN] = 0.f;
    } else {
        if (tid == 0) any = 0;
        __syncthreads();
        if (eidx_u[2*tid + 1] != 0u) atomicOr(&any, 1);
        __syncthreads();
        if (tid == 0) *flag = (any == 0) ? 1 : 0; // 1 => int64
    }
}

// ---------------- pass B: bin edges into 196 fixed-stride bucket regions ----------------
// record = (dst&255)<<16 | src   (src < 50000 < 2^16)
__global__ __launch_bounds__(1024) void binB_k(const void* __restrict__ eidx,
                                               const int* __restrict__ flag,
                                               int* __restrict__ bktCur,
                                               unsigned* __restrict__ binned){
    __shared__ int hist[NBKT];
    __shared__ int resv[NBKT];
    __shared__ int cur[NBKT];
    const int tid = threadIdx.x;
    const int f = *flag;
    if (tid < NBKT){ hist[tid] = 0; cur[tid] = 0; }
    __syncthreads();

    int bkt[4]; unsigned pk[4];
    #pragma unroll
    for (int u = 0; u < 4; ++u){
        long e = (long)blockIdx.x*4096 + u*1024 + tid;
        if (e < NE){
            int s = ld_idx(eidx, f, e);
            int d = ld_idx(eidx, f, (long)NE + e);
            bkt[u] = d >> 8;
            pk[u]  = ((unsigned)(d & 255) << 16) | (unsigned)s;
            atomicAdd(&hist[bkt[u]], 1);
        } else bkt[u] = -1;
    }
    __syncthreads();
    if (tid < NBKT && hist[tid] > 0)
        resv[tid] = atomicAdd(&bktCur[tid], hist[tid]);
    __syncthreads();
    #pragma unroll
    for (int u = 0; u < 4; ++u){
        if (bkt[u] >= 0){
            int p = resv[bkt[u]] + atomicAdd(&cur[bkt[u]], 1);
            if ((unsigned)p < MAXB) binned[(long)bkt[u]*MAXB + p] = pk[u];
        }
    }
}

// ---------------- pass C (+bound): per-bucket LDS counting sort with 16-PADDED slots ----------
// rp[v]..re[v] is a multiple-of-16 region; pad slots hold sentinel index NN (scale 0).
// blocks >= NBKT compute graph segment boundaries from sorted batch vector.
__global__ __launch_bounds__(256) void passC_k(const int* __restrict__ bktCur,
                                               const unsigned* __restrict__ binned,
                                               int* __restrict__ rp, int* __restrict__ re,
                                               float* __restrict__ dinv,
                                               unsigned short* __restrict__ cn,
                                               const void* __restrict__ batv,
                                               const int* __restrict__ flag,
                                               int* __restrict__ gstart){
    __shared__ unsigned staged[MAXB];
    __shared__ int cnt[256];
    __shared__ int sc[256];
    __shared__ int cur[256];
    const int tid = threadIdx.x;
    if (blockIdx.x >= NBKT){
        int i = (blockIdx.x - NBKT)*256 + tid;
        if (i >= NN) return;
        int f = *flag;
        int b = ld_idx(batv, f, i);
        if (i == 0){
            for (int g = 0; g <= b; ++g) gstart[g] = 0;
        } else {
            int p = ld_idx(batv, f, i-1);
            for (int g = p+1; g <= b; ++g) gstart[g] = i;
        }
        if (i == NN-1){
            for (int g = b+1; g <= NGR; ++g) gstart[g] = NN;
        }
        return;
    }
    const int b = blockIdx.x;
    int n = bktCur[b]; if (n > MAXB) n = MAXB;
    const long base = (long)b*MAXB;

    cnt[tid] = 0;
    __syncthreads();
    for (int i = tid; i < n; i += 256){
        unsigned rec = binned[base + i];
        staged[i] = rec;
        atomicAdd(&cnt[rec >> 16], 1);
    }
    __syncthreads();
    int c  = cnt[tid];
    int pc = (c + 15) & ~15;          // padded count, multiple of 16
    sc[tid] = pc;
    __syncthreads();
    for (int off = 1; off < 256; off <<= 1){
        int t = (tid >= off) ? sc[tid - off] : 0;
        __syncthreads();
        if (tid >= off) sc[tid] += t;
        __syncthreads();
    }
    int lo = sc[tid] - pc;
    int v = b*256 + tid;
    if (v < NN){
        rp[v]   = (int)base + lo;
        re[v]   = (int)base + lo + pc;
        dinv[v] = rsqrtf((float)(c + 1));
    }
    cur[tid] = lo;
    __syncthreads();
    for (int i = tid; i < n; i += 256){
        unsigned rec = staged[i];
        int j = rec >> 16;
        int p = atomicAdd(&cur[j], 1);
        cn[base + p] = (unsigned short)(rec & 0xFFFFu);
    }
    __syncthreads();
    // fill this node's pad slots with the zero-scale sentinel index
    for (int i = c; i < pc; ++i)
        cn[base + lo + i] = (unsigned short)NN;
}

// ---------------- fused GEMM + (optional) pool-of-previous-layer ----------------
// blocks [0,GEMMB): T(plane-split u8, per-row pow2 scale) = quant(dinv[m] * (A @ W)).
//   A-tile (64x128 fp16, 16 KB) staged in XOR-swizzled LDS via coalesced loads.
//   T written with NONTEMPORAL stores into plane (wc>>6) to keep L2 clean for agg.
// blocks [GEMMB, GEMMB+POOLB) (POOL only): global max pool of h into gbuf[...,lpool,...].
template<bool F32IN, bool POOL>
__global__ __launch_bounds__(256) void gemm_k(const void* __restrict__ Av,
                                              const _Float16* __restrict__ WT,
                                              const float* __restrict__ dinv,
                                              unsigned char* __restrict__ T,
                                              float* __restrict__ scl,
                                              const _Float16* __restrict__ h,
                                              const int* __restrict__ gstart,
                                              unsigned* __restrict__ gbuf, int lpool){
    const int tid  = threadIdx.x;
    if (POOL && blockIdx.x >= GEMMB){
        __shared__ float red[4][FD];
        int pid = blockIdx.x - GEMMB;
        int g = pid >> 3, part = pid & 7;
        int lane = tid & 63, w = tid >> 6;
        int s0 = gstart[g], s1 = gstart[g+1];
        int len = s1 - s0;
        int chunk = (len + 7) >> 3;
        int a = s0 + part*chunk;
        int b = min(a + chunk, s1);
        int sub = (b - a + 3) >> 2;
        int aa = a + w*sub;
        int bb = min(aa + sub, b);
        const half2t* h2 = reinterpret_cast<const half2t*>(h);
        float m0 = 0.f, m1 = 0.f;
        for (int i = aa; i < bb; ++i){
            half2t x = h2[(long)i*64 + lane];
            m0 = fmaxf(m0, (float)x[0]);
            m1 = fmaxf(m1, (float)x[1]);
        }
        red[w][2*lane]   = m0;
        red[w][2*lane+1] = m1;
        __syncthreads();
        if (w == 0){
            float r0 = fmaxf(fmaxf(red[0][2*lane],   red[1][2*lane]),
                             fmaxf(red[2][2*lane],   red[3][2*lane]));
            float r1 = fmaxf(fmaxf(red[0][2*lane+1], red[1][2*lane+1]),
                             fmaxf(red[2][2*lane+1], red[3][2*lane+1]));
            atomicMax(&gbuf[g*(NLAY*FD) + lpool*FD + 2*lane    ], __float_as_uint(r0));
            atomicMax(&gbuf[g*(NLAY*FD) + lpool*FD + 2*lane + 1], __float_as_uint(r1));
        }
        return;
    }

    __shared__ unsigned char Asb[64*256];     // 16 KB swizzled A-tile
    __shared__ float hm[64][2];
    const int lane = tid & 63;
    const int wid  = tid >> 6;
    const int wr   = (wid >> 1) * 32;
    const int wc   = (wid & 1) * 64;
    const long r0  = (long)blockIdx.x * 64;
    const int lr   = lane & 15;
    const int lk   = (lane >> 4) * 8;

    // ---- stage A-tile: thread t covers row tr = t>>2, 32-col chunk ch = t&3 (64 B) ----
    {
        int tr = tid >> 2, ch = tid & 3;
        long grow = r0 + tr;
        bool ok = grow < NN;
        #pragma unroll
        for (int i = 0; i < 4; ++i){
            half8 a;
            if constexpr (F32IN){
                const float* A = (const float*)Av;
                if (ok){
                    float4 u0 = *reinterpret_cast<const float4*>(A + grow*FD + ch*32 + i*8);
                    float4 u1 = *reinterpret_cast<const float4*>(A + grow*FD + ch*32 + i*8 + 4);
                    a[0]=(_Float16)u0.x; a[1]=(_Float16)u0.y; a[2]=(_Float16)u0.z; a[3]=(_Float16)u0.w;
                    a[4]=(_Float16)u1.x; a[5]=(_Float16)u1.y; a[6]=(_Float16)u1.z; a[7]=(_Float16)u1.w;
                } else a = (half8)(_Float16)0;
            } else {
                const _Float16* A = (const _Float16*)Av;
                a = ok ? *reinterpret_cast<const half8*>(A + grow*FD + ch*32 + i*8)
                       : (half8)(_Float16)0;
            }
            int off = (tr*256 + ch*64 + i*16) ^ ((tr & 7) << 4);
            *reinterpret_cast<half8*>(Asb + off) = a;
        }
    }

    half8 wf[4][4];
    #pragma unroll
    for (int n = 0; n < 4; ++n)
        #pragma unroll
        for (int kk = 0; kk < 4; ++kk)
            wf[n][kk] = *reinterpret_cast<const half8*>(WT + (wc + n*16 + lr)*FD + kk*32 + lk);

    f32x4 acc[2][4];
    #pragma unroll
    for (int m = 0; m < 2; ++m)
        #pragma unroll
        for (int n = 0; n < 4; ++n)
            acc[m][n] = (f32x4){0.f,0.f,0.f,0.f};

    __syncthreads();

    #pragma unroll
    for (int kk = 0; kk < 4; ++kk){
        half8 af[2];
        #pragma unroll
        for (int m = 0; m < 2; ++m){
            int rl = wr + m*16 + lr;
            int off = (rl*256 + kk*64 + (lane>>4)*16) ^ ((rl & 7) << 4);
            af[m] = *reinterpret_cast<const half8*>(Asb + off);
        }
        #pragma unroll
        for (int m = 0; m < 2; ++m)
            #pragma unroll
            for (int n = 0; n < 4; ++n)
                acc[m][n] = __builtin_amdgcn_mfma_f32_16x16x32_f16(wf[n][kk], af[m], acc[m][n], 0, 0, 0);
    }

    // ---- per-row pow2-scaled u8 quantization ----
    float amax[2] = {0.f, 0.f};
    float dim[2];
    #pragma unroll
    for (int m = 0; m < 2; ++m){
        long row = r0 + wr + m*16 + lr;
        float di = (row < NN) ? dinv[row] : 0.f;
        dim[m] = di;
        #pragma unroll
        for (int n = 0; n < 4; ++n)
            #pragma unroll
            for (int q = 0; q < 4; ++q)
                amax[m] = fmaxf(amax[m], fabsf(acc[m][n][q] * di));
    }
    #pragma unroll
    for (int m = 0; m < 2; ++m){
        amax[m] = fmaxf(amax[m], __shfl_xor(amax[m], 16));
        amax[m] = fmaxf(amax[m], __shfl_xor(amax[m], 32));
    }
    __syncthreads();
    if (lane < 16){
        hm[wr + lane     ][wid & 1] = amax[0];
        hm[wr + 16 + lane][wid & 1] = amax[1];
    }
    __syncthreads();
    unsigned char* Tp = T + (size_t)(wc >> 6) * PLSZ;   // destination plane
    #pragma unroll
    for (int m = 0; m < 2; ++m){
        long row = r0 + wr + m*16 + lr;
        if (row >= NN) continue;
        int rl = wr + m*16 + lr;
        float rm = fmaxf(hm[rl][0], hm[rl][1]);
        // smallest power of 2 >= rm/127
        float a = rm * (1.0f/127.0f);
        unsigned bits = __float_as_uint(a);
        unsigned e = bits >> 23;
        unsigned sb = ((bits & 0x7fffffu) ? e + 1u : e) << 23;
        float scale = __uint_as_float(sb);
        float inv = __uint_as_float((254u - (sb >> 23)) << 23);   // exact 1/scale
        if (rm < 1e-30f){ scale = 0.f; inv = 0.f; }
        float di = dim[m];
        #pragma unroll
        for (int n = 0; n < 4; ++n){
            int q0 = __float2int_rn(acc[m][n][0] * di * inv) + 128;
            int q1 = __float2int_rn(acc[m][n][1] * di * inv) + 128;
            int q2 = __float2int_rn(acc[m][n][2] * di * inv) + 128;
            int q3 = __float2int_rn(acc[m][n][3] * di * inv) + 128;
            unsigned p = (unsigned)q0 | ((unsigned)q1 << 8) |
                         ((unsigned)q2 << 16) | ((unsigned)q3 << 24);
            __builtin_nontemporal_store(p,
                reinterpret_cast<unsigned*>(Tp + (size_t)row*64 + n*16 + (lane>>4)*4));
        }
        if ((wid & 1) == 0 && lane < 16)
            scl[row] = scale;
    }
}

// ---------------- aggregation: XCD-steered planes, quarter-per-node, 16-deep u8 bursts ------
// grid = AGGB = 6256. x=bid&7: fh=x>>2 steers plane 0 to XCDs 0-3, plane 1 to XCDs 4-7;
// nb=(bid>>3)*4+(x&3) is the 16-node block (guarded). One plane = 3.2 MB -> fits a 4 MB
// XCD L2, so steady-state gathers are L2 HITS. Quarter (16 lanes x 4 B) covers one 64 B
// half-row; decode = 4 cvt_f32_ubyte + 4 fma. Edge lists 16-padded with zero-scale sentinel.
__global__ __launch_bounds__(256) void agg_k(const unsigned char* __restrict__ t,
                                             const float* __restrict__ scl,
                                             const int* __restrict__ rp,
                                             const int* __restrict__ re,
                                             const unsigned short* __restrict__ cn,
                                             const float* __restrict__ dinv,
                                             const float* __restrict__ bias,
                                             _Float16* __restrict__ h){
    const int bid = blockIdx.x;
    const int x   = bid & 7;
    const int fh  = x >> 2;
    const int nb  = (bid >> 3)*4 + (x & 3);
    if (nb >= NN/16) return;
    const int lane = threadIdx.x & 63;
    const int wid  = threadIdx.x >> 6;
    const int r    = lane & 15;                 // 4 B slot within the 64 B half-row
    const int qb   = lane & 48;                 // quarter base lane
    const int v    = nb*16 + wid*4 + (lane >> 4);
    const unsigned* plane = reinterpret_cast<const unsigned*>(t + (size_t)fh * PLSZ);

    float acc[4] = {0.f, 0.f, 0.f, 0.f};
    float ssum = 0.f;

    const int e0 = rp[v], e1 = re[v];           // padded: (e1-e0) % 16 == 0
    for (int base = e0; base < e1; base += 16){
        int ce = (int)cn[base + r];             // 16 edge indices for this quarter's node
        float scv = scl[ce];
        #pragma unroll
        for (int j = 0; j < 16; ++j){
            int s    = __shfl(ce,  qb + j);
            float sc = __shfl(scv, qb + j);
            unsigned g = plane[(size_t)s*16 + r];
            acc[0] = fmaf((float)( g        & 255u), sc, acc[0]);
            acc[1] = fmaf((float)((g >>  8) & 255u), sc, acc[1]);
            acc[2] = fmaf((float)((g >> 16) & 255u), sc, acc[2]);
            acc[3] = fmaf((float)( g >> 24        ), sc, acc[3]);
            ssum += sc;
        }
    }
    // self term
    {
        float sc = scl[v];
        unsigned g = plane[(size_t)v*16 + r];
        acc[0] = fmaf((float)( g        & 255u), sc, acc[0]);
        acc[1] = fmaf((float)((g >>  8) & 255u), sc, acc[1]);
        acc[2] = fmaf((float)((g >> 16) & 255u), sc, acc[2]);
        acc[3] = fmaf((float)( g >> 24        ), sc, acc[3]);
        ssum += sc;
    }

    float dis = dinv[v];
    float4 b = reinterpret_cast<const float4*>(bias)[fh*16 + r];
    float bb[4] = {b.x, b.y, b.z, b.w};
    half4 o;
    #pragma unroll
    for (int i = 0; i < 4; ++i)
        o[i] = (_Float16)fmaxf(fmaf(acc[i] - 128.f*ssum, dis, bb[i]), 0.f);
    unsigned long long uu;
    __builtin_memcpy(&uu, &o, 8);
    __builtin_nontemporal_store(uu,
        reinterpret_cast<unsigned long long*>(h + (size_t)v*FD + fh*64 + r*4));
}

// ---------------- standalone pool (last layer only) ----------------
__global__ __launch_bounds__(256) void pool_k(const _Float16* __restrict__ h,
                                              const int* __restrict__ gstart,
                                              unsigned* __restrict__ gbuf, int l){
    __shared__ float red[4][FD];
    int g = blockIdx.x, part = blockIdx.y;
    int tid = threadIdx.x, lane = tid & 63, w = tid >> 6;
    int s0 = gstart[g], s1 = gstart[g+1];
    int len = s1 - s0;
    int chunk = (len + 7) >> 3;
    int a = s0 + part*chunk;
    int b = min(a + chunk, s1);
    int sub = (b - a + 3) >> 2;
    int aa = a + w*sub;
    int bb = min(aa + sub, b);
    const half2t* h2 = reinterpret_cast<const half2t*>(h);
    float m0 = 0.f, m1 = 0.f;
    for (int i = aa; i < bb; ++i){
        half2t x = h2[(long)i*64 + lane];
        m0 = fmaxf(m0, (float)x[0]);
        m1 = fmaxf(m1, (float)x[1]);
    }
    red[w][2*lane]   = m0;
    red[w][2*lane+1] = m1;
    __syncthreads();
    if (w == 0){
        float r0 = fmaxf(fmaxf(red[0][2*lane],   red[1][2*lane]),
                         fmaxf(red[2][2*lane],   red[3][2*lane]));
        float r1 = fmaxf(fmaxf(red[0][2*lane+1], red[1][2*lane+1]),
                         fmaxf(red[2][2*lane+1], red[3][2*lane+1]));
        atomicMax(&gbuf[g*(NLAY*FD) + l*FD + 2*lane    ], __float_as_uint(r0));
        atomicMax(&gbuf[g*(NLAY*FD) + l*FD + 2*lane + 1], __float_as_uint(r1));
    }
}

// ---------------- head: 1024 threads/block, k-split x4 + LDS reduce ----------------
__global__ __launch_bounds__(1024) void head_k(const unsigned* __restrict__ gbuf,
                                               const float* __restrict__ Wlin,
                                               const float* __restrict__ blin,
                                               const float* __restrict__ Wout,
                                               const float* __restrict__ bout,
                                               float* __restrict__ out){
    __shared__ float gs[NLAY*FD];
    __shared__ float ps[4][NLIN];
    __shared__ float us[NLIN];
    int g = blockIdx.x, tid = threadIdx.x;
    if (tid < NLAY*FD) gs[tid] = __uint_as_float(gbuf[g*(NLAY*FD) + tid]);
    __syncthreads();
    int c = tid & 255;
    int q = tid >> 8;
    float a = 0.f;
    #pragma unroll 8
    for (int k = q*128; k < q*128 + 128; ++k)
        a = fmaf(gs[k], Wlin[k*NLIN + c], a);
    ps[q][c] = a;
    __syncthreads();
    if (tid < NLIN){
        float u = ps[0][tid] + ps[1][tid] + ps[2][tid] + ps[3][tid] + blin[tid];
        us[tid] = fmaxf(u, 0.f);
    }
    __syncthreads();
    if (tid < NOUTF){
        float o = bout[tid];
        #pragma unroll 8
        for (int k = 0; k < NLIN; ++k) o = fmaf(us[k], Wout[k*NOUTF + tid], o);
        out[g*NOUTF + tid] = o;
    }
}

// ---------------- launch ----------------
extern "C" void kernel_launch(void* const* d_in, const int* in_sizes, int n_in,
                              void* d_out, int out_size, void* d_ws, size_t ws_size,
                              hipStream_t stream){
    const float* x    = (const float*)d_in[0];
    const void*  eidx = d_in[1];
    const void*  batv = d_in[2];
    const float* Wsp  = (const float*)d_in[4];
    const float* bsp  = (const float*)d_in[5];
    const float* Wlin = (const float*)d_in[6];
    const float* blin = (const float*)d_in[7];
    const float* Wout = (const float*)d_in[8];
    const float* bout = (const float*)d_in[9];
    float* out = (float*)d_out;

    uintptr_t cur = (uintptr_t)d_ws;
    auto alloc = [&](size_t bytes)->void*{
        cur = (cur + 255) & ~(uintptr_t)255;
        void* p = (void*)cur;
        cur += bytes;
        return p;
    };
    unsigned char* t = (unsigned char*)alloc(2*PLSZ);            // 2 planes of u8 half-rows
    float* scl   = (float*)alloc((size_t)(NN+1)*4);              // per-row pow2 scales
    _Float16* h  = (_Float16*)alloc((size_t)NN*FD*2);            // row-major [NN][128] fp16
    _Float16* WT = (_Float16*)alloc((size_t)NLAY*FD*FD*2);
    unsigned* binned = (unsigned*)alloc((size_t)NBKT*MAXB*4);
    unsigned short* cn = (unsigned short*)alloc((size_t)NBKT*MAXB*2);
    int*   rp    = (int*)  alloc((size_t)NN*4);
    int*   re    = (int*)  alloc((size_t)NN*4);
    float* dinv  = (float*)alloc((size_t)NN*4);
    int*   gst   = (int*)  alloc((NGR+1)*4);
    int*   flag  = (int*)  alloc(4);
    // contiguous zero region: bktCur | gbuf
    int*      bktCur = (int*)     alloc((size_t)NBKT*4);
    unsigned* gbuf   = (unsigned*)alloc((size_t)NGR*NLAY*FD*4);
    int zero_n = (int)((cur - (uintptr_t)bktCur + 3) / 4);
    int zb = (zero_n + 255) / 256;

    pre_k  <<<256 + zb + 2, 256, 0, stream>>>((const unsigned*)eidx, Wsp, WT,
                                              bktCur, zero_n, zb, t, scl, flag);
    binB_k <<<NBKT, 1024, 0, stream>>>(eidx, flag, bktCur, binned);
    passC_k<<<NBKT + (NN+255)/256, 256, 0, stream>>>(bktCur, binned, rp, re, dinv, cn,
                                                     batv, flag, gst);

    for (int l = 0; l < NLAY; ++l){
        const void* hin = (l == 0) ? (const void*)x : (const void*)h;
        if (l == 0)
            gemm_k<true ,false><<<GEMMB, 256, 0, stream>>>(hin, WT, dinv, t, scl,
                                                           h, gst, gbuf, 0);
        else
            gemm_k<false,true ><<<GEMMB + POOLB, 256, 0, stream>>>(hin, WT + (size_t)l*FD*FD,
                                                                   dinv, t, scl, h, gst, gbuf, l-1);
        agg_k<<<AGGB, 256, 0, stream>>>(t, scl, rp, re, cn, dinv, bsp + (size_t)l*FD, h);
    }
    pool_k<<<dim3(NGR, 8), 256, 0, stream>>>(h, gst, gbuf, NLAY-1);
    head_k<<<NGR, 1024, 0, stream>>>(gbuf, Wlin, blin, Wout, bout, out);
}

// Round 21
// 229.266 us; speedup vs baseline: 1.0281x; 1.0281x over previous
//
#include <hip/hip_runtime.h>
#include <stdint.h>

#define NN    50000
#define NE    800000
#define FD    128
#define NLAY  4
#define NLIN  256
#define NOUTF 10
#define NGR   64
#define NBKT  196     // ceil(NN/256) buckets of 256 nodes
#define MAXB  8192    // per-bucket capacity incl. 16-padding (mean ~6100 -> safe)
#define GEMMB 782     // ceil(NN/64) gemm blocks
#define POOLB 512     // NGR * 8 pool blocks

typedef _Float16 half8  __attribute__((ext_vector_type(8)));
typedef _Float16 half4  __attribute__((ext_vector_type(4)));
typedef _Float16 half2t __attribute__((ext_vector_type(2)));
typedef float    f32x4  __attribute__((ext_vector_type(4)));

__device__ __forceinline__ int ld_idx(const void* p, int flag, long i){
    return flag ? (int)((const long long*)p)[i] : ((const int*)p)[i];
}

// ---------------- merged prologue: prep_w | zero(bktCur+gbuf) | sentinel | detect ----------
// If int64 (values < 2^31), every odd 32-bit word of edge_index is 0.
__global__ __launch_bounds__(256) void pre_k(const unsigned* __restrict__ eidx_u,
                                             const float* __restrict__ Ws,
                                             _Float16* __restrict__ WT,
                                             int* __restrict__ zbase, int zn, int zb,
                                             int* __restrict__ sent,
                                             float* __restrict__ scl,
                                             int* __restrict__ flag){
    __shared__ int any;
    const int b = blockIdx.x, tid = threadIdx.x;
    if (b < 256){
        // WT[l][c][k] = Ws[l][k][c]
        int idx = b*256 + tid;
        int l = idx >> 14;
        int r = idx & 16383;
        int c = r >> 7, k = r & 127;
        WT[idx] = (_Float16)Ws[(l<<14) + (k<<7) + c];
    } else if (b < 256 + zb){
        int i = (b-256)*256 + tid;
        if (i < zn) zbase[i] = 0;
    } else if (b == 256 + zb){
        if (tid < FD/4) sent[tid] = 0;            // zero-sentinel u8 row NN of t (128 B)
        if (tid == 0) scl[NN] = 0.f;              // sentinel scale = 0 => pad edges contribute 0
    } else {
        if (tid == 0) any = 0;
        __syncthreads();
        if (eidx_u[2*tid + 1] != 0u) atomicOr(&any, 1);
        __syncthreads();
        if (tid == 0) *flag = (any == 0) ? 1 : 0; // 1 => int64
    }
}

// ---------------- pass B: bin edges into 196 fixed-stride bucket regions ----------------
// record = (dst&255)<<16 | src   (src < 50000 < 2^16)
__global__ __launch_bounds__(1024) void binB_k(const void* __restrict__ eidx,
                                               const int* __restrict__ flag,
                                               int* __restrict__ bktCur,
                                               unsigned* __restrict__ binned){
    __shared__ int hist[NBKT];
    __shared__ int resv[NBKT];
    __shared__ int cur[NBKT];
    const int tid = threadIdx.x;
    const int f = *flag;
    if (tid < NBKT){ hist[tid] = 0; cur[tid] = 0; }
    __syncthreads();

    int bkt[4]; unsigned pk[4];
    #pragma unroll
    for (int u = 0; u < 4; ++u){
        long e = (long)blockIdx.x*4096 + u*1024 + tid;
        if (e < NE){
            int s = ld_idx(eidx, f, e);
            int d = ld_idx(eidx, f, (long)NE + e);
            bkt[u] = d >> 8;
            pk[u]  = ((unsigned)(d & 255) << 16) | (unsigned)s;
            atomicAdd(&hist[bkt[u]], 1);
        } else bkt[u] = -1;
    }
    __syncthreads();
    if (tid < NBKT && hist[tid] > 0)
        resv[tid] = atomicAdd(&bktCur[tid], hist[tid]);
    __syncthreads();
    #pragma unroll
    for (int u = 0; u < 4; ++u){
        if (bkt[u] >= 0){
            int p = resv[bkt[u]] + atomicAdd(&cur[bkt[u]], 1);
            if ((unsigned)p < MAXB) binned[(long)bkt[u]*MAXB + p] = pk[u];
        }
    }
}

// ---------------- pass C (+bound): per-bucket LDS counting sort with 16-PADDED slots ----------
// rp[v]..re[v] is a multiple-of-16 region; pad slots hold sentinel index NN (scale 0).
// blocks >= NBKT compute graph segment boundaries from sorted batch vector.
__global__ __launch_bounds__(256) void passC_k(const int* __restrict__ bktCur,
                                               const unsigned* __restrict__ binned,
                                               int* __restrict__ rp, int* __restrict__ re,
                                               float* __restrict__ dinv,
                                               unsigned short* __restrict__ cn,
                                               const void* __restrict__ batv,
                                               const int* __restrict__ flag,
                                               int* __restrict__ gstart){
    __shared__ unsigned staged[MAXB];
    __shared__ int cnt[256];
    __shared__ int sc[256];
    __shared__ int cur[256];
    const int tid = threadIdx.x;
    if (blockIdx.x >= NBKT){
        int i = (blockIdx.x - NBKT)*256 + tid;
        if (i >= NN) return;
        int f = *flag;
        int b = ld_idx(batv, f, i);
        if (i == 0){
            for (int g = 0; g <= b; ++g) gstart[g] = 0;
        } else {
            int p = ld_idx(batv, f, i-1);
            for (int g = p+1; g <= b; ++g) gstart[g] = i;
        }
        if (i == NN-1){
            for (int g = b+1; g <= NGR; ++g) gstart[g] = NN;
        }
        return;
    }
    const int b = blockIdx.x;
    int n = bktCur[b]; if (n > MAXB) n = MAXB;
    const long base = (long)b*MAXB;

    cnt[tid] = 0;
    __syncthreads();
    for (int i = tid; i < n; i += 256){
        unsigned rec = binned[base + i];
        staged[i] = rec;
        atomicAdd(&cnt[rec >> 16], 1);
    }
    __syncthreads();
    int c  = cnt[tid];
    int pc = (c + 15) & ~15;          // padded count, multiple of 16
    sc[tid] = pc;
    __syncthreads();
    for (int off = 1; off < 256; off <<= 1){
        int t = (tid >= off) ? sc[tid - off] : 0;
        __syncthreads();
        if (tid >= off) sc[tid] += t;
        __syncthreads();
    }
    int lo = sc[tid] - pc;
    int v = b*256 + tid;
    if (v < NN){
        rp[v]   = (int)base + lo;
        re[v]   = (int)base + lo + pc;
        dinv[v] = rsqrtf((float)(c + 1));
    }
    cur[tid] = lo;
    __syncthreads();
    for (int i = tid; i < n; i += 256){
        unsigned rec = staged[i];
        int j = rec >> 16;
        int p = atomicAdd(&cur[j], 1);
        cn[base + p] = (unsigned short)(rec & 0xFFFFu);
    }
    __syncthreads();
    // fill this node's pad slots with the zero-scale sentinel index
    for (int i = c; i < pc; ++i)
        cn[base + lo + i] = (unsigned short)NN;
}

// ---------------- fused GEMM + (optional) pool-of-previous-layer ----------------
// blocks [0,GEMMB): T[M,128](u8, per-row pow2 scale) = quant(dinv[m] * (A[M,128] @ W)).
//   A-tile (64x128 fp16, 16 KB) staged in XOR-swizzled LDS via coalesced loads;
//   fragments read with ds_read_b128 (2-way conflicts = free).
// blocks [GEMMB, GEMMB+POOLB) (POOL only): global max pool of h into gbuf[...,lpool,...].
// Safe fusion: both halves only READ h; agg (the NEXT dispatch) is what overwrites h.
template<bool F32IN, bool POOL>
__global__ __launch_bounds__(256) void gemm_k(const void* __restrict__ Av,
                                              const _Float16* __restrict__ WT,
                                              const float* __restrict__ dinv,
                                              unsigned char* __restrict__ T,
                                              float* __restrict__ scl,
                                              const _Float16* __restrict__ h,
                                              const int* __restrict__ gstart,
                                              unsigned* __restrict__ gbuf, int lpool){
    const int tid  = threadIdx.x;
    if (POOL && blockIdx.x >= GEMMB){
        __shared__ float red[4][FD];
        int pid = blockIdx.x - GEMMB;
        int g = pid >> 3, part = pid & 7;
        int lane = tid & 63, w = tid >> 6;
        int s0 = gstart[g], s1 = gstart[g+1];
        int len = s1 - s0;
        int chunk = (len + 7) >> 3;
        int a = s0 + part*chunk;
        int b = min(a + chunk, s1);
        int sub = (b - a + 3) >> 2;
        int aa = a + w*sub;
        int bb = min(aa + sub, b);
        const half2t* h2 = reinterpret_cast<const half2t*>(h);
        float m0 = 0.f, m1 = 0.f;
        for (int i = aa; i < bb; ++i){
            half2t x = h2[(long)i*64 + lane];
            m0 = fmaxf(m0, (float)x[0]);
            m1 = fmaxf(m1, (float)x[1]);
        }
        red[w][2*lane]   = m0;
        red[w][2*lane+1] = m1;
        __syncthreads();
        if (w == 0){
            float r0 = fmaxf(fmaxf(red[0][2*lane],   red[1][2*lane]),
                             fmaxf(red[2][2*lane],   red[3][2*lane]));
            float r1 = fmaxf(fmaxf(red[0][2*lane+1], red[1][2*lane+1]),
                             fmaxf(red[2][2*lane+1], red[3][2*lane+1]));
            atomicMax(&gbuf[g*(NLAY*FD) + lpool*FD + 2*lane    ], __float_as_uint(r0));
            atomicMax(&gbuf[g*(NLAY*FD) + lpool*FD + 2*lane + 1], __float_as_uint(r1));
        }
        return;
    }

    __shared__ unsigned char Asb[64*256];     // 16 KB swizzled A-tile
    __shared__ float hm[64][2];
    const int lane = tid & 63;
    const int wid  = tid >> 6;
    const int wr   = (wid >> 1) * 32;
    const int wc   = (wid & 1) * 64;
    const long r0  = (long)blockIdx.x * 64;
    const int lr   = lane & 15;
    const int lk   = (lane >> 4) * 8;

    // ---- stage A-tile: thread t covers row tr = t>>2, 32-col chunk ch = t&3 (64 B) ----
    {
        int tr = tid >> 2, ch = tid & 3;
        long grow = r0 + tr;
        bool ok = grow < NN;
        #pragma unroll
        for (int i = 0; i < 4; ++i){
            half8 a;
            if constexpr (F32IN){
                const float* A = (const float*)Av;
                if (ok){
                    float4 u0 = *reinterpret_cast<const float4*>(A + grow*FD + ch*32 + i*8);
                    float4 u1 = *reinterpret_cast<const float4*>(A + grow*FD + ch*32 + i*8 + 4);
                    a[0]=(_Float16)u0.x; a[1]=(_Float16)u0.y; a[2]=(_Float16)u0.z; a[3]=(_Float16)u0.w;
                    a[4]=(_Float16)u1.x; a[5]=(_Float16)u1.y; a[6]=(_Float16)u1.z; a[7]=(_Float16)u1.w;
                } else a = (half8)(_Float16)0;
            } else {
                const _Float16* A = (const _Float16*)Av;
                a = ok ? *reinterpret_cast<const half8*>(A + grow*FD + ch*32 + i*8)
                       : (half8)(_Float16)0;
            }
            int off = (tr*256 + ch*64 + i*16) ^ ((tr & 7) << 4);
            *reinterpret_cast<half8*>(Asb + off) = a;
        }
    }

    half8 wf[4][4];
    #pragma unroll
    for (int n = 0; n < 4; ++n)
        #pragma unroll
        for (int kk = 0; kk < 4; ++kk)
            wf[n][kk] = *reinterpret_cast<const half8*>(WT + (wc + n*16 + lr)*FD + kk*32 + lk);

    f32x4 acc[2][4];
    #pragma unroll
    for (int m = 0; m < 2; ++m)
        #pragma unroll
        for (int n = 0; n < 4; ++n)
            acc[m][n] = (f32x4){0.f,0.f,0.f,0.f};

    __syncthreads();

    #pragma unroll
    for (int kk = 0; kk < 4; ++kk){
        half8 af[2];
        #pragma unroll
        for (int m = 0; m < 2; ++m){
            int rl = wr + m*16 + lr;
            int off = (rl*256 + kk*64 + (lane>>4)*16) ^ ((rl & 7) << 4);
            af[m] = *reinterpret_cast<const half8*>(Asb + off);
        }
        #pragma unroll
        for (int m = 0; m < 2; ++m)
            #pragma unroll
            for (int n = 0; n < 4; ++n)
                acc[m][n] = __builtin_amdgcn_mfma_f32_16x16x32_f16(wf[n][kk], af[m], acc[m][n], 0, 0, 0);
    }

    // ---- per-row pow2-scaled u8 quantization ----
    float amax[2] = {0.f, 0.f};
    float dim[2];
    #pragma unroll
    for (int m = 0; m < 2; ++m){
        long row = r0 + wr + m*16 + lr;
        float di = (row < NN) ? dinv[row] : 0.f;
        dim[m] = di;
        #pragma unroll
        for (int n = 0; n < 4; ++n)
            #pragma unroll
            for (int q = 0; q < 4; ++q)
                amax[m] = fmaxf(amax[m], fabsf(acc[m][n][q] * di));
    }
    #pragma unroll
    for (int m = 0; m < 2; ++m){
        amax[m] = fmaxf(amax[m], __shfl_xor(amax[m], 16));
        amax[m] = fmaxf(amax[m], __shfl_xor(amax[m], 32));
    }
    __syncthreads();
    if (lane < 16){
        hm[wr + lane     ][wid & 1] = amax[0];
        hm[wr + 16 + lane][wid & 1] = amax[1];
    }
    __syncthreads();
    #pragma unroll
    for (int m = 0; m < 2; ++m){
        long row = r0 + wr + m*16 + lr;
        if (row >= NN) continue;
        int rl = wr + m*16 + lr;
        float rm = fmaxf(hm[rl][0], hm[rl][1]);
        // smallest power of 2 >= rm/127
        float a = rm * (1.0f/127.0f);
        unsigned bits = __float_as_uint(a);
        unsigned e = bits >> 23;
        unsigned sb = ((bits & 0x7fffffu) ? e + 1u : e) << 23;
        float scale = __uint_as_float(sb);
        float inv = __uint_as_float((254u - (sb >> 23)) << 23);   // exact 1/scale
        if (rm < 1e-30f){ scale = 0.f; inv = 0.f; }
        float di = dim[m];
        #pragma unroll
        for (int n = 0; n < 4; ++n){
            int q0 = __float2int_rn(acc[m][n][0] * di * inv) + 128;
            int q1 = __float2int_rn(acc[m][n][1] * di * inv) + 128;
            int q2 = __float2int_rn(acc[m][n][2] * di * inv) + 128;
            int q3 = __float2int_rn(acc[m][n][3] * di * inv) + 128;
            unsigned p = (unsigned)q0 | ((unsigned)q1 << 8) |
                         ((unsigned)q2 << 16) | ((unsigned)q3 << 24);
            *reinterpret_cast<unsigned*>(T + (size_t)row*FD + wc + n*16 + (lane>>4)*4) = p;
        }
        if ((wid & 1) == 0 && lane < 16)
            scl[row] = scale;
    }
}

// ---------------- aggregation: quarter-per-node, 16-deep unrolled u8 gather pipeline ----------
// Wave = 4 nodes (one per 16-lane quarter); block = 16 nodes; grid = 3125.
// u8 rows are 128 B = ONE cache line per edge. Per-row pow2 scale from a 200 KB L2-resident
// table, loaded per-lane with the edge indices and shfl-broadcast. value = scale*(u-128):
// acc += scale*u (exact f32: 8-bit mantissa x pow2), bias folded via -128*sum(scale).
// Edge lists 16-padded with the zero-scale sentinel -> mask-free unrolled inner loop.
__global__ __launch_bounds__(256) void agg_k(const unsigned char* __restrict__ t,
                                             const float* __restrict__ scl,
                                             const int* __restrict__ rp,
                                             const int* __restrict__ re,
                                             const unsigned short* __restrict__ cn,
                                             const float* __restrict__ dinv,
                                             const float* __restrict__ bias,
                                             _Float16* __restrict__ h){
    const int lane = threadIdx.x & 63;
    const int wid  = threadIdx.x >> 6;
    const int r    = lane & 15;                 // 8 B slot within the 128 B row
    const int qb   = lane & 48;                 // quarter base lane
    const int v    = blockIdx.x*16 + wid*4 + (lane >> 4);
    const uint2* tq = reinterpret_cast<const uint2*>(t);   // row stride = 16 uint2

    float acc[8];
    #pragma unroll
    for (int i = 0; i < 8; ++i) acc[i] = 0.f;
    float ssum = 0.f;

    const int e0 = rp[v], e1 = re[v];           // padded: (e1-e0) % 16 == 0
    for (int base = e0; base < e1; base += 16){
        int ce = (int)cn[base + r];             // 16 edge indices for this quarter's node
        float scv = scl[ce];                    // their scales (hot 200 KB table)
        #pragma unroll
        for (int j = 0; j < 16; ++j){
            int s    = __shfl(ce,  qb + j);
            float sc = __shfl(scv, qb + j);
            uint2 g = tq[(size_t)s*16 + r];
            acc[0] = fmaf((float)( g.x        & 255u), sc, acc[0]);
            acc[1] = fmaf((float)((g.x >>  8) & 255u), sc, acc[1]);
            acc[2] = fmaf((float)((g.x >> 16) & 255u), sc, acc[2]);
            acc[3] = fmaf((float)( g.x >> 24        ), sc, acc[3]);
            acc[4] = fmaf((float)( g.y        & 255u), sc, acc[4]);
            acc[5] = fmaf((float)((g.y >>  8) & 255u), sc, acc[5]);
            acc[6] = fmaf((float)((g.y >> 16) & 255u), sc, acc[6]);
            acc[7] = fmaf((float)( g.y >> 24        ), sc, acc[7]);
            ssum += sc;
        }
    }
    // self term
    {
        float sc = scl[v];
        uint2 g = tq[(size_t)v*16 + r];
        acc[0] = fmaf((float)( g.x        & 255u), sc, acc[0]);
        acc[1] = fmaf((float)((g.x >>  8) & 255u), sc, acc[1]);
        acc[2] = fmaf((float)((g.x >> 16) & 255u), sc, acc[2]);
        acc[3] = fmaf((float)( g.x >> 24        ), sc, acc[3]);
        acc[4] = fmaf((float)( g.y        & 255u), sc, acc[4]);
        acc[5] = fmaf((float)((g.y >>  8) & 255u), sc, acc[5]);
        acc[6] = fmaf((float)((g.y >> 16) & 255u), sc, acc[6]);
        acc[7] = fmaf((float)( g.y >> 24        ), sc, acc[7]);
        ssum += sc;
    }

    float dis = dinv[v];
    float4 b0 = reinterpret_cast<const float4*>(bias)[2*r];
    float4 b1 = reinterpret_cast<const float4*>(bias)[2*r+1];
    float bb[8] = {b0.x,b0.y,b0.z,b0.w,b1.x,b1.y,b1.z,b1.w};
    half8 o;
    #pragma unroll
    for (int i = 0; i < 8; ++i)
        o[i] = (_Float16)fmaxf(fmaf(acc[i] - 128.f*ssum, dis, bb[i]), 0.f);
    reinterpret_cast<half8*>(h)[(size_t)v*16 + r] = o;
}

// ---------------- standalone pool (last layer only) ----------------
__global__ __launch_bounds__(256) void pool_k(const _Float16* __restrict__ h,
                                              const int* __restrict__ gstart,
                                              unsigned* __restrict__ gbuf, int l){
    __shared__ float red[4][FD];
    int g = blockIdx.x, part = blockIdx.y;
    int tid = threadIdx.x, lane = tid & 63, w = tid >> 6;
    int s0 = gstart[g], s1 = gstart[g+1];
    int len = s1 - s0;
    int chunk = (len + 7) >> 3;
    int a = s0 + part*chunk;
    int b = min(a + chunk, s1);
    int sub = (b - a + 3) >> 2;
    int aa = a + w*sub;
    int bb = min(aa + sub, b);
    const half2t* h2 = reinterpret_cast<const half2t*>(h);
    float m0 = 0.f, m1 = 0.f;
    for (int i = aa; i < bb; ++i){
        half2t x = h2[(long)i*64 + lane];
        m0 = fmaxf(m0, (float)x[0]);
        m1 = fmaxf(m1, (float)x[1]);
    }
    red[w][2*lane]   = m0;
    red[w][2*lane+1] = m1;
    __syncthreads();
    if (w == 0){
        float r0 = fmaxf(fmaxf(red[0][2*lane],   red[1][2*lane]),
                         fmaxf(red[2][2*lane],   red[3][2*lane]));
        float r1 = fmaxf(fmaxf(red[0][2*lane+1], red[1][2*lane+1]),
                         fmaxf(red[2][2*lane+1], red[3][2*lane+1]));
        atomicMax(&gbuf[g*(NLAY*FD) + l*FD + 2*lane    ], __float_as_uint(r0));
        atomicMax(&gbuf[g*(NLAY*FD) + l*FD + 2*lane + 1], __float_as_uint(r1));
    }
}

// ---------------- head: 1024 threads/block, k-split x4 + LDS reduce ----------------
__global__ __launch_bounds__(1024) void head_k(const unsigned* __restrict__ gbuf,
                                               const float* __restrict__ Wlin,
                                               const float* __restrict__ blin,
                                               const float* __restrict__ Wout,
                                               const float* __restrict__ bout,
                                               float* __restrict__ out){
    __shared__ float gs[NLAY*FD];
    __shared__ float ps[4][NLIN];
    __shared__ float us[NLIN];
    int g = blockIdx.x, tid = threadIdx.x;
    if (tid < NLAY*FD) gs[tid] = __uint_as_float(gbuf[g*(NLAY*FD) + tid]);
    __syncthreads();
    int c = tid & 255;
    int q = tid >> 8;
    float a = 0.f;
    #pragma unroll 8
    for (int k = q*128; k < q*128 + 128; ++k)
        a = fmaf(gs[k], Wlin[k*NLIN + c], a);
    ps[q][c] = a;
    __syncthreads();
    if (tid < NLIN){
        float u = ps[0][tid] + ps[1][tid] + ps[2][tid] + ps[3][tid] + blin[tid];
        us[tid] = fmaxf(u, 0.f);
    }
    __syncthreads();
    if (tid < NOUTF){
        float o = bout[tid];
        #pragma unroll 8
        for (int k = 0; k < NLIN; ++k) o = fmaf(us[k], Wout[k*NOUTF + tid], o);
        out[g*NOUTF + tid] = o;
    }
}

// ---------------- launch ----------------
extern "C" void kernel_launch(void* const* d_in, const int* in_sizes, int n_in,
                              void* d_out, int out_size, void* d_ws, size_t ws_size,
                              hipStream_t stream){
    const float* x    = (const float*)d_in[0];
    const void*  eidx = d_in[1];
    const void*  batv = d_in[2];
    const float* Wsp  = (const float*)d_in[4];
    const float* bsp  = (const float*)d_in[5];
    const float* Wlin = (const float*)d_in[6];
    const float* blin = (const float*)d_in[7];
    const float* Wout = (const float*)d_in[8];
    const float* bout = (const float*)d_in[9];
    float* out = (float*)d_out;

    uintptr_t cur = (uintptr_t)d_ws;
    auto alloc = [&](size_t bytes)->void*{
        cur = (cur + 255) & ~(uintptr_t)255;
        void* p = (void*)cur;
        cur += bytes;
        return p;
    };
    unsigned char* t = (unsigned char*)alloc((size_t)(NN+1)*FD); // u8 rows + zero-sentinel row NN
    float* scl   = (float*)alloc((size_t)(NN+1)*4);              // per-row pow2 scales
    _Float16* h  = (_Float16*)alloc((size_t)NN*FD*2);            // row-major [NN][128] fp16
    _Float16* WT = (_Float16*)alloc((size_t)NLAY*FD*FD*2);
    unsigned* binned = (unsigned*)alloc((size_t)NBKT*MAXB*4);
    unsigned short* cn = (unsigned short*)alloc((size_t)NBKT*MAXB*2);
    int*   rp    = (int*)  alloc((size_t)NN*4);
    int*   re    = (int*)  alloc((size_t)NN*4);
    float* dinv  = (float*)alloc((size_t)NN*4);
    int*   gst   = (int*)  alloc((NGR+1)*4);
    int*   flag  = (int*)  alloc(4);
    // contiguous zero region: bktCur | gbuf
    int*      bktCur = (int*)     alloc((size_t)NBKT*4);
    unsigned* gbuf   = (unsigned*)alloc((size_t)NGR*NLAY*FD*4);
    int zero_n = (int)((cur - (uintptr_t)bktCur + 3) / 4);
    int zb = (zero_n + 255) / 256;

    pre_k  <<<256 + zb + 2, 256, 0, stream>>>((const unsigned*)eidx, Wsp, WT,
                                              bktCur, zero_n, zb,
                                              (int*)(t + (size_t)NN*FD), scl, flag);
    binB_k <<<NBKT, 1024, 0, stream>>>(eidx, flag, bktCur, binned);
    passC_k<<<NBKT + (NN+255)/256, 256, 0, stream>>>(bktCur, binned, rp, re, dinv, cn,
                                                     batv, flag, gst);

    for (int l = 0; l < NLAY; ++l){
        const void* hin = (l == 0) ? (const void*)x : (const void*)h;
        if (l == 0)
            gemm_k<true ,false><<<GEMMB, 256, 0, stream>>>(hin, WT, dinv, t, scl,
                                                           h, gst, gbuf, 0);
        else
            gemm_k<false,true ><<<GEMMB + POOLB, 256, 0, stream>>>(hin, WT + (size_t)l*FD*FD,
                                                                   dinv, t, scl, h, gst, gbuf, l-1);
        agg_k<<<NN/16, 256, 0, stream>>>(t, scl, rp, re, cn, dinv, bsp + (size_t)l*FD, h);
    }
    pool_k<<<dim3(NGR, 8), 256, 0, stream>>>(h, gst, gbuf, NLAY-1);
    head_k<<<NGR, 1024, 0, stream>>>(gbuf, Wlin, blin, Wout, bout, out);
}